// Round 7
// baseline (426.039 us; speedup 1.0000x reference)
//
#include <hip/hip_runtime.h>

#define NROW 8192
#define DIN  512
#define DOUT 256
#define NCHUNK 1024
#define CLEN 8     // NCHUNK*CLEN == NROW
#define NGRP 32    // groups of chunks
#define GLEN 32    // chunks per group
#define JCH 8      // j-chunks for rank counting

// ---------------- workspace layout (bytes) ----------------
constexpr size_t OFF_H      = 0;                              // 8192*256*4
constexpr size_t OFF_S1     = OFF_H + (size_t)NROW*DOUT*4;    // ---- memset region
constexpr size_t OFF_S2     = OFF_S1 + NROW*4;
constexpr size_t OFF_RK1    = OFF_S2 + NROW*4;                // rank of s1 (sort perm)
constexpr size_t OFF_KRK    = OFF_RK1 + NROW*4;               // k_i counts
constexpr size_t OFF_RK2    = OFF_KRK + NROW*4;               // query order (s2 desc)
constexpr size_t OFF_GLO    = OFF_RK2 + NROW*4;               // [NGRP][DOUT]
constexpr size_t OFF_GHI    = OFF_GLO + (size_t)NGRP*DOUT*4;
constexpr size_t OFF_GSLO   = OFF_GHI + (size_t)NGRP*DOUT*4;  // [NGRP]
constexpr size_t OFF_GSHI   = OFF_GSLO + 128;
constexpr size_t MEMSET_LEN = OFF_GSHI + 128 - OFF_S1;        // ---- end memset
constexpr size_t OFF_PERM   = OFF_GSHI + 128;
constexpr size_t OFF_WHI    = OFF_PERM + NROW*4;
constexpr size_t OFF_WLO    = OFF_WHI + NROW*4;
constexpr size_t OFF_S2S    = OFF_WLO + NROW*4;               // s2 sorted by rank2
constexpr size_t OFF_QPERM  = OFF_S2S + NROW*4;
constexpr size_t OFF_KSORT  = OFF_QPERM + NROW*4;             // k sorted (nondecreasing)
constexpr size_t OFF_CSLO   = OFF_KSORT + NROW*4;             // [NCHUNK]
constexpr size_t OFF_CSHI   = OFF_CSLO + (size_t)NCHUNK*4;
constexpr size_t OFF_TLO    = OFF_CSHI + (size_t)NCHUNK*4;    // [NCHUNK][DOUT]
constexpr size_t OFF_THI    = OFF_TLO + (size_t)NCHUNK*DOUT*4;
constexpr size_t WS_NEED    = OFF_THI + (size_t)NCHUNK*DOUT*4;

// ------- kernel 1: h = x @ W^T  (fp32, 64x64 tile) + fused s1/s2 ----------
__global__ __launch_bounds__(256) void gemm_h(const float* __restrict__ x,
                                              const float* __restrict__ W,
                                              const float* __restrict__ a1,
                                              const float* __restrict__ a2,
                                              float* __restrict__ h,
                                              float* __restrict__ s1,
                                              float* __restrict__ s2) {
  __shared__ float xs[64][68];
  __shared__ float ws[64][68];
  const int tid = threadIdx.x;
  const int rowBase = blockIdx.x * 64;
  const int colBase = blockIdx.y * 64;
  const int ty = tid >> 4, tx = tid & 15;
  float acc[4][4] = {};
  for (int k0 = 0; k0 < DIN; k0 += 64) {
#pragma unroll
    for (int i = 0; i < 4; ++i) {
      int s = i * 256 + tid;
      int r = s >> 4;
      int kk = (s & 15) << 2;
      float4 v = *(const float4*)(x + (size_t)(rowBase + r) * DIN + k0 + kk);
      xs[kk + 0][r] = v.x; xs[kk + 1][r] = v.y; xs[kk + 2][r] = v.z; xs[kk + 3][r] = v.w;
      float4 u = *(const float4*)(W + (size_t)(colBase + r) * DIN + k0 + kk);
      ws[kk + 0][r] = u.x; ws[kk + 1][r] = u.y; ws[kk + 2][r] = u.z; ws[kk + 3][r] = u.w;
    }
    __syncthreads();
#pragma unroll
    for (int kk = 0; kk < 64; ++kk) {
      float4 av = *(const float4*)&xs[kk][ty << 2];
      float4 bv = *(const float4*)&ws[kk][tx << 2];
      float a[4] = {av.x, av.y, av.z, av.w};
      float b[4] = {bv.x, bv.y, bv.z, bv.w};
#pragma unroll
      for (int r = 0; r < 4; ++r)
#pragma unroll
        for (int c = 0; c < 4; ++c) acc[r][c] = fmaf(a[r], b[c], acc[r][c]);
    }
    __syncthreads();
  }
#pragma unroll
  for (int r = 0; r < 4; ++r) {
    float4 o = make_float4(acc[r][0], acc[r][1], acc[r][2], acc[r][3]);
    *(float4*)(h + (size_t)(rowBase + (ty << 2) + r) * DOUT + colBase + (tx << 2)) = o;
  }
  float4 A1 = *(const float4*)(a1 + colBase + (tx << 2));
  float4 A2 = *(const float4*)(a2 + colBase + (tx << 2));
#pragma unroll
  for (int r = 0; r < 4; ++r) {
    float p1 = acc[r][0] * A1.x + acc[r][1] * A1.y + acc[r][2] * A1.z + acc[r][3] * A1.w;
    float p2 = acc[r][0] * A2.x + acc[r][1] * A2.y + acc[r][2] * A2.z + acc[r][3] * A2.w;
#pragma unroll
    for (int m = 1; m < 16; m <<= 1) {
      p1 += __shfl_xor(p1, m);
      p2 += __shfl_xor(p2, m);
    }
    if (tx == 0) {
      int row = rowBase + (ty << 2) + r;
      atomicAdd(&s1[row], p1);
      atomicAdd(&s2[row], p2);
    }
  }
}

// ------- kernel 2: triple rank count --------------------------------------
// rank1[i] = #{j: s1[j] < s1[i] or (== and j<i)}     (data sort order)
// krank[i] = #{j: s1[j] <= -s2[i]}                   (query boundary k)
// rank2[i] = #{j: s2[j] > s2[i] or (== and j<i)}     (query sort: k nondecr.)
__global__ __launch_bounds__(256) void rank_count(const float* __restrict__ s1,
                                                  const float* __restrict__ s2,
                                                  int* __restrict__ rank1,
                                                  int* __restrict__ krank,
                                                  int* __restrict__ rank2) {
  __shared__ float sj1[1024];
  __shared__ float sj2[1024];
  const int t = threadIdx.x;
  const int ib = blockIdx.x, jc = blockIdx.y;
  const int j0 = jc * 1024;
  *(float4*)&sj1[t << 2] = *(const float4*)(s1 + j0 + (t << 2));
  *(float4*)&sj2[t << 2] = *(const float4*)(s2 + j0 + (t << 2));
  const int i = ib * 256 + t;
  const float v1 = s1[i];
  const float s2i = s2[i];
  const float v2m = -s2i;
  __syncthreads();
  int c1 = 0, ck = 0, c2 = 0;
#pragma unroll 4
  for (int q = 0; q < 256; ++q) {
    float4 a = *(const float4*)&sj1[q << 2];
    float4 b = *(const float4*)&sj2[q << 2];
    int jg = j0 + (q << 2);
    c1 += (int)(a.x < v1) + (int)((a.x == v1) & (jg + 0 < i));
    c1 += (int)(a.y < v1) + (int)((a.y == v1) & (jg + 1 < i));
    c1 += (int)(a.z < v1) + (int)((a.z == v1) & (jg + 2 < i));
    c1 += (int)(a.w < v1) + (int)((a.w == v1) & (jg + 3 < i));
    ck += (int)(a.x <= v2m) + (int)(a.y <= v2m) + (int)(a.z <= v2m) + (int)(a.w <= v2m);
    c2 += (int)(b.x > s2i) + (int)((b.x == s2i) & (jg + 0 < i));
    c2 += (int)(b.y > s2i) + (int)((b.y == s2i) & (jg + 1 < i));
    c2 += (int)(b.z > s2i) + (int)((b.z == s2i) & (jg + 2 < i));
    c2 += (int)(b.w > s2i) + (int)((b.w == s2i) & (jg + 3 < i));
  }
  atomicAdd(&rank1[i], c1);
  atomicAdd(&krank[i], ck);
  atomicAdd(&rank2[i], c2);
}

// ------- kernel 3: scatter data-sort + query-sort arrays -------------------
// |s1|,|s2| small so unshifted exp is safe in fp32 (validated R5/R6).
__global__ __launch_bounds__(256) void scatter_w(const float* __restrict__ s1,
                                                 const float* __restrict__ s2,
                                                 const int* __restrict__ rank1,
                                                 const int* __restrict__ krank,
                                                 const int* __restrict__ rank2,
                                                 int* __restrict__ perm,
                                                 float* __restrict__ w_hi,
                                                 float* __restrict__ w_lo,
                                                 int* __restrict__ qperm,
                                                 int* __restrict__ ksort,
                                                 float* __restrict__ s2s) {
  const int i = blockIdx.x * 256 + threadIdx.x;
  const float v = s1[i];
  const int r1 = rank1[i];
  perm[r1] = i;
  w_hi[r1] = __expf(v);
  w_lo[r1] = __expf(0.2f * v);
  const int r2 = rank2[i];
  qperm[r2] = i;
  ksort[r2] = krank[i];
  s2s[r2] = s2[i];
}

// ------- kernel 4: per-chunk totals (CLEN=8) + group atomics ---------------
__global__ __launch_bounds__(256) void chunk_totals(const float* __restrict__ h,
                                                    const int* __restrict__ perm,
                                                    const float* __restrict__ w_hi,
                                                    const float* __restrict__ w_lo,
                                                    float* __restrict__ T_lo,
                                                    float* __restrict__ T_hi,
                                                    float* __restrict__ G_lo,
                                                    float* __restrict__ G_hi,
                                                    float* __restrict__ cs_lo,
                                                    float* __restrict__ cs_hi,
                                                    float* __restrict__ GS_lo,
                                                    float* __restrict__ GS_hi) {
  const int d = threadIdx.x, c = blockIdx.x, g = c >> 5;
  const int j0 = c * CLEN;
  float tlo = 0.f, thi = 0.f;
#pragma unroll
  for (int e = 0; e < CLEN; e += 4) {
    int4 p4 = *(const int4*)(perm + j0 + e);
    float4 wl4 = *(const float4*)(w_lo + j0 + e);
    float4 wh4 = *(const float4*)(w_hi + j0 + e);
    float h0 = h[(size_t)p4.x * DOUT + d];
    float h1 = h[(size_t)p4.y * DOUT + d];
    float h2 = h[(size_t)p4.z * DOUT + d];
    float h3 = h[(size_t)p4.w * DOUT + d];
    tlo += wl4.x * h0 + wl4.y * h1 + wl4.z * h2 + wl4.w * h3;
    thi += wh4.x * h0 + wh4.y * h1 + wh4.z * h2 + wh4.w * h3;
  }
  T_lo[c * DOUT + d] = tlo;
  T_hi[c * DOUT + d] = thi;
  atomicAdd(&G_lo[g * DOUT + d], tlo);
  atomicAdd(&G_hi[g * DOUT + d], thi);
  if (d < 64) {
    float wl = (d < CLEN) ? w_lo[j0 + d] : 0.f;
    float wh = (d < CLEN) ? w_hi[j0 + d] : 0.f;
#pragma unroll
    for (int off = 4; off > 0; off >>= 1) {
      wl += __shfl_down(wl, off);
      wh += __shfl_down(wh, off);
    }
    if (d == 0) {
      cs_lo[c] = wl; cs_hi[c] = wh;
      atomicAdd(&GS_lo[g], wl); atomicAdd(&GS_hi[g], wh);
    }
  }
}

// lower_bound (count of elements < target) over sorted int array of 8192
__device__ __forceinline__ int lb8192(const int* __restrict__ a, int target) {
  int pos = 0;
#pragma unroll
  for (int b = 4096; b > 0; b >>= 1)
    if (a[pos + b - 1] < target) pos += b;
  return pos;
}

// ------- kernel 5: two-level offsets + walk chunk + emit output rows -------
// Block c keeps the running PreLo/SufHi (vector, per-thread col d) and the
// scalar denominators in REGISTERS while walking its 8 sorted positions, and
// writes finished out rows for queries whose k in [j0, j0+CLEN).
__global__ __launch_bounds__(256) void emit_out(const float* __restrict__ h,
                                                const int* __restrict__ perm,
                                                const float* __restrict__ w_hi,
                                                const float* __restrict__ w_lo,
                                                const float* __restrict__ T_lo,
                                                const float* __restrict__ T_hi,
                                                const float* __restrict__ G_lo,
                                                const float* __restrict__ G_hi,
                                                const float* __restrict__ cs_lo,
                                                const float* __restrict__ cs_hi,
                                                const float* __restrict__ GS_lo,
                                                const float* __restrict__ GS_hi,
                                                const int* __restrict__ qperm,
                                                const int* __restrict__ ksort,
                                                const float* __restrict__ s2s,
                                                float* __restrict__ out) {
  __shared__ float sh_sc[2];
  const int d = threadIdx.x, c = blockIdx.x;
  const int g = c >> 5, cin = c & 31;
  const int j0 = c * CLEN;
  // ---- scalar group/chunk offsets (wave 0 computes, LDS broadcast) ----
  if (d < 64) {
    float sp = 0.f, st = 0.f;
    if (d < 32) {
      float gl = GS_lo[d], gh = GS_hi[d];
      float cl = cs_lo[g * GLEN + d], ch = cs_hi[g * GLEN + d];
      sp = ((d < g) ? gl : 0.f) + ((d < cin) ? cl : 0.f);
      st = ((d > g) ? gh : 0.f) + ((d > cin) ? ch : 0.f);
    }
#pragma unroll
    for (int off = 32; off > 0; off >>= 1) {
      sp += __shfl_down(sp, off);
      st += __shfl_down(st, off);
    }
    if (d == 0) { sh_sc[0] = sp; sh_sc[1] = st; }
  }
  // ---- vector offsets: group level then chunk level ----
  float rl = 0.f, tail = 0.f;
#pragma unroll 8
  for (int p = 0; p < NGRP; ++p) {
    float gl = G_lo[p * DOUT + d];
    float gh = G_hi[p * DOUT + d];
    rl   += (p < g) ? gl : 0.f;
    tail += (p > g) ? gh : 0.f;
  }
  const int cbase = g * GLEN;
#pragma unroll 8
  for (int q = 0; q < GLEN; ++q) {
    float vl = T_lo[(cbase + q) * DOUT + d];
    float vh = T_hi[(cbase + q) * DOUT + d];
    rl   += (q < cin) ? vl : 0.f;
    tail += (q > cin) ? vh : 0.f;
  }
  // ---- gather this chunk's rows + weights ----
  float hv[CLEN], wlv[CLEN], whv[CLEN];
  float ownHi = 0.f, ownHiS = 0.f;
#pragma unroll
  for (int e = 0; e < CLEN; e += 4) {
    int4 p4 = *(const int4*)(perm + j0 + e);
    float4 wl4 = *(const float4*)(w_lo + j0 + e);
    float4 wh4 = *(const float4*)(w_hi + j0 + e);
    hv[e + 0] = h[(size_t)p4.x * DOUT + d];
    hv[e + 1] = h[(size_t)p4.y * DOUT + d];
    hv[e + 2] = h[(size_t)p4.z * DOUT + d];
    hv[e + 3] = h[(size_t)p4.w * DOUT + d];
    wlv[e + 0] = wl4.x; wlv[e + 1] = wl4.y; wlv[e + 2] = wl4.z; wlv[e + 3] = wl4.w;
    whv[e + 0] = wh4.x; whv[e + 1] = wh4.y; whv[e + 2] = wh4.z; whv[e + 3] = wh4.w;
    ownHi += wh4.x * hv[e] + wh4.y * hv[e + 1] + wh4.z * hv[e + 2] + wh4.w * hv[e + 3];
    ownHiS += wh4.x + wh4.y + wh4.z + wh4.w;
  }
  __syncthreads();
  const float pres = sh_sc[0], tails = sh_sc[1];
  // ---- query range for this chunk ----
  const int qlo = lb8192(ksort, j0);
  int qhi = lb8192(ksort, j0 + CLEN);
  // ---- walk boundaries, emit ----
  float pre_v = rl, suf_v = tail + ownHi;
  float pre_sc = pres, suf_sc = tails + ownHiS;
  int q = qlo;
#pragma unroll
  for (int e = 0; e < CLEN; ++e) {
    const int kb = j0 + e;
    while (q < qhi && ksort[q] == kb) {
      const int iq = qperm[q];
      const float c2 = s2s[q];
      const float fh = __expf(c2);
      const float fl = __expf(0.2f * c2);
      const float inv = 1.f / (fh * suf_sc + fl * pre_sc);
      out[(size_t)iq * DOUT + d] = (fh * suf_v + fl * pre_v) * inv;
      ++q;
    }
    pre_v += wlv[e] * hv[e];  suf_v -= whv[e] * hv[e];
    pre_sc += w_lo[j0 + e];   suf_sc -= whv[e];  // scalar lo weight broadcast-loaded
  }
  if (c == NCHUNK - 1) {
    // queries with k == 8192 (all-lo): final state
    while (q < NROW) {
      const int iq = qperm[q];
      const float c2 = s2s[q];
      const float fh = __expf(c2);
      const float fl = __expf(0.2f * c2);
      const float inv = 1.f / (fh * suf_sc + fl * pre_sc);
      out[(size_t)iq * DOUT + d] = (fh * suf_v + fl * pre_v) * inv;
      ++q;
    }
  }
}

extern "C" void kernel_launch(void* const* d_in, const int* in_sizes, int n_in,
                              void* d_out, int out_size, void* d_ws, size_t ws_size,
                              hipStream_t stream) {
  const float* x  = (const float*)d_in[0];
  const float* W  = (const float*)d_in[2];
  const float* a1 = (const float*)d_in[3];
  const float* a2 = (const float*)d_in[4];
  float* out = (float*)d_out;

  char* ws = (char*)d_ws;
  if (ws_size < WS_NEED) ws = (char*)d_in[1];  // fall back to unused adj buffer

  float* h     = (float*)(ws + OFF_H);
  float* s1    = (float*)(ws + OFF_S1);
  float* s2    = (float*)(ws + OFF_S2);
  int*   rank1 = (int*)  (ws + OFF_RK1);
  int*   krank = (int*)  (ws + OFF_KRK);
  int*   rank2 = (int*)  (ws + OFF_RK2);
  float* G_lo  = (float*)(ws + OFF_GLO);
  float* G_hi  = (float*)(ws + OFF_GHI);
  float* GS_lo = (float*)(ws + OFF_GSLO);
  float* GS_hi = (float*)(ws + OFF_GSHI);
  int*   perm  = (int*)  (ws + OFF_PERM);
  float* w_hi  = (float*)(ws + OFF_WHI);
  float* w_lo  = (float*)(ws + OFF_WLO);
  float* s2s   = (float*)(ws + OFF_S2S);
  int*   qperm = (int*)  (ws + OFF_QPERM);
  int*   ksort = (int*)  (ws + OFF_KSORT);
  float* cs_lo = (float*)(ws + OFF_CSLO);
  float* cs_hi = (float*)(ws + OFF_CSHI);
  float* T_lo  = (float*)(ws + OFF_TLO);
  float* T_hi  = (float*)(ws + OFF_THI);

  hipMemsetAsync(s1, 0, MEMSET_LEN, stream);

  gemm_h<<<dim3(NROW / 64, DOUT / 64), 256, 0, stream>>>(x, W, a1, a2, h, s1, s2);
  rank_count<<<dim3(NROW / 256, JCH), 256, 0, stream>>>(s1, s2, rank1, krank, rank2);
  scatter_w<<<NROW / 256, 256, 0, stream>>>(s1, s2, rank1, krank, rank2,
                                            perm, w_hi, w_lo, qperm, ksort, s2s);
  chunk_totals<<<NCHUNK, 256, 0, stream>>>(h, perm, w_hi, w_lo, T_lo, T_hi,
                                           G_lo, G_hi, cs_lo, cs_hi, GS_lo, GS_hi);
  emit_out<<<NCHUNK, 256, 0, stream>>>(h, perm, w_hi, w_lo, T_lo, T_hi,
                                       G_lo, G_hi, cs_lo, cs_hi, GS_lo, GS_hi,
                                       qperm, ksort, s2s, out);
}